// Round 4
// baseline (276.589 us; speedup 1.0000x reference)
//
#include <hip/hip_runtime.h>

#define N_NODES_C 100000
#define N_EDGES_C 1200000
#define NUM_GRAPHS_C 64
#define D_C 64
#define NPASS_C 8
#define BN_EPS_C 1e-5f
#define SCAN_B 391     // ceil(100000/256)
#define SH_N 16        // count shards
#define PLANE_W 25000  // u32 words per shard plane (4 byte-counters each)

typedef unsigned short u16;
typedef unsigned int u32;
typedef unsigned char u8;

using frag_ab = __attribute__((ext_vector_type(8))) short;  // 8 bf16 (4 VGPRs)
using f32x4   = __attribute__((ext_vector_type(4))) float;

__device__ __forceinline__ u16 f2bf(float f) {  // RTNE
    u32 x = __float_as_uint(f);
    x += 0x7fffu + ((x >> 16) & 1u);
    return (u16)(x >> 16);
}
__device__ __forceinline__ float bf2f(u16 u) {
    return __uint_as_float(((u32)u) << 16);
}

// ------------- prep: x->bf16, W->bf16[n][k], zero row ---------------------
__global__ void k_prep(const float* __restrict__ x,
                       const float* __restrict__ W1, const float* __restrict__ W2,
                       u16* __restrict__ Xb, u16* __restrict__ Wb1,
                       u16* __restrict__ Wb2, u16* __restrict__ T) {
    int i = blockIdx.x * 256 + threadIdx.x;
    int base = i * 4;
    if (base < N_NODES_C * D_C) {
        float4 f = *(const float4*)(x + base);
        ushort4 o;
        o.x = f2bf(f.x); o.y = f2bf(f.y); o.z = f2bf(f.z); o.w = f2bf(f.w);
        *(ushort4*)(Xb + base) = o;
    }
    if (i < 4096) {  // W[k][n] -> Wb[n][k]
        int n = i >> 6, k = i & 63;
        Wb1[i] = f2bf(W1[k * 64 + n]);
        Wb2[i] = f2bf(W2[k * 64 + n]);
    }
    if (i < 64) T[(size_t)N_NODES_C * 64 + i] = 0;  // zero row (survives gemms)
}

// ------------- count: 16-way sharded, byte-packed counters ----------------
// R2/R3 both hit a ~54 us floor = 192 atomics/line x ~280 ns per-line serial
// RMW (each atomic write-through to HBM: the ~37 MB WRITE excess). Shard by
// s = e & 15 (recomputable from edge index in k_place -> no shard array) and
// byte-pack 4 nodes/u32: 25k lines, 48 ops/line, conflict depth ~12.
// Per-(shard,node) count <= deg <= ~45 < 255: bytes cannot carry.
__global__ void __launch_bounds__(256) k_count(
        const int* __restrict__ dst, u32* __restrict__ cntp,
        u8* __restrict__ pos8) {
    const int nquads = N_EDGES_C / 4;
    int tid = blockIdx.x * 256 + threadIdx.x;
    int nth = gridDim.x * 256;
    const int4* dst4 = (const int4*)dst;
    for (int i = tid; i < nquads; i += nth) {
        int4 d4 = dst4[i];
        int dd[4] = {d4.x, d4.y, d4.z, d4.w};
        u32 pw = 0;
#pragma unroll
        for (int k = 0; k < 4; ++k) {
            int s = ((i & 3) << 2) | k;  // (4i+k) & 15
            int d = dd[k];
            u32 sh = 8u * (d & 3);
            u32 old = atomicAdd(&cntp[s * PLANE_W + (d >> 2)], 1u << sh);
            pw |= ((old >> sh) & 0xffu) << (8 * k);
        }
        ((u32*)pos8)[i] = pw;
    }
}

// --------------------- scan: cntp -> cnt, start, startsh ------------------
__global__ void __launch_bounds__(256) k_scan1(const u32* __restrict__ cntp,
                                               int* __restrict__ cnt,
                                               int* __restrict__ start,
                                               int* __restrict__ bsum) {
    __shared__ int sh[256];
    int t = threadIdx.x;
    int i = blockIdx.x * 256 + t;
    int c = 0;
    if (i < N_NODES_C) {
        u32 shmt = 8u * (i & 3);
        int w = i >> 2;
#pragma unroll
        for (int s = 0; s < SH_N; ++s)
            c += (int)((cntp[s * PLANE_W + w] >> shmt) & 0xffu);
    }
    int val = c;
    sh[t] = val;
    __syncthreads();
#pragma unroll
    for (int off = 1; off < 256; off <<= 1) {
        int y = (t >= off) ? sh[t - off] : 0;
        __syncthreads();
        val += y;
        sh[t] = val;
        __syncthreads();
    }
    if (i < N_NODES_C) { start[i] = val - c; cnt[i] = c; }  // block-local excl
    if (t == 255) bsum[blockIdx.x] = val;                   // block total
}

__global__ void __launch_bounds__(512) k_scan2(int* __restrict__ bsum) {
    __shared__ int sh[512];
    int t = threadIdx.x;
    int c = (t < SCAN_B) ? bsum[t] : 0;
    int val = c;
    sh[t] = val;
    __syncthreads();
#pragma unroll
    for (int off = 1; off < 512; off <<= 1) {
        int y = (t >= off) ? sh[t - off] : 0;
        __syncthreads();
        val += y;
        sh[t] = val;
        __syncthreads();
    }
    if (t < SCAN_B) bsum[t] = val - c;  // exclusive block offsets, in place
}

__global__ void __launch_bounds__(256) k_scan3(int* __restrict__ start,
                                               const int* __restrict__ bsum,
                                               const u32* __restrict__ cntp,
                                               int* __restrict__ startsh) {
    int i = blockIdx.x * 256 + threadIdx.x;
    if (i >= N_NODES_C) return;
    int base = start[i] + bsum[blockIdx.x];
    start[i] = base;
    u32 shmt = 8u * (i & 3);
    int w = i >> 2;
    int run = base;
#pragma unroll
    for (int s = 0; s < SH_N; ++s) {
        startsh[s * N_NODES_C + i] = run;
        run += (int)((cntp[s * PLANE_W + w] >> shmt) & 0xffu);
    }
}

// ------------------- place: atomic-free CSR fill, XCD-swizzled ------------
// slot = startsh[e&15][dst] + pos8[e]. Dense 4.8 MB CSR: every written line
// fully covered; per-XCD active slice ~600 KB lives in its private L2.
__global__ void __launch_bounds__(256) k_place(
        const int* __restrict__ src, const int* __restrict__ dst,
        const u8* __restrict__ pos8, const int* __restrict__ startsh,
        int* __restrict__ col) {
    int pass = blockIdx.x & (NPASS_C - 1);
    int chunk = blockIdx.x >> 3;
    int nchunks = gridDim.x >> 3;
    const int RANGE = N_NODES_C / NPASS_C;  // 12500
    int lo = pass * RANGE;
    int hi = (pass == NPASS_C - 1) ? N_NODES_C : lo + RANGE;
    const int nquads = N_EDGES_C / 4;  // 300000
    int tid = chunk * 256 + threadIdx.x;
    int nthreads = nchunks * 256;
    const int4* dst4 = (const int4*)dst;
    const int4* src4 = (const int4*)src;
    const u32* pos4 = (const u32*)pos8;
    for (int i = tid; i < nquads; i += nthreads) {
        int4 d4 = dst4[i];
        int dd[4] = {d4.x, d4.y, d4.z, d4.w};
        bool in0 = dd[0] >= lo && dd[0] < hi;
        bool in1 = dd[1] >= lo && dd[1] < hi;
        bool in2 = dd[2] >= lo && dd[2] < hi;
        bool in3 = dd[3] >= lo && dd[3] < hi;
        if (in0 | in1 | in2 | in3) {
            int4 s4 = src4[i];
            u32 p4 = pos4[i];
            int ss[4] = {s4.x, s4.y, s4.z, s4.w};
            bool in[4] = {in0, in1, in2, in3};
#pragma unroll
            for (int k = 0; k < 4; ++k) {
                if (in[k]) {
                    int s = ((i & 3) << 2) | k;  // (4i+k) & 15
                    int slot = startsh[s * N_NODES_C + dd[k]] + (int)((p4 >> (8 * k)) & 0xffu);
                    col[(size_t)(u32)slot] = ss[k];
                }
            }
        }
    }
}

// ------------------- GEMM via MFMA 16x16x32 bf16 --------------------------
__global__ void __launch_bounds__(256) k_gemm_mfma(
        const u16* __restrict__ Xb, const u16* __restrict__ Wb,
        const int* __restrict__ cnt, u16* __restrict__ T) {
    int lane = threadIdx.x & 63;
    int q = lane >> 4, ln = lane & 15;
    int wave = blockIdx.x * 4 + (threadIdx.x >> 6);
    int nwaves = gridDim.x * 4;
    frag_ab bfr[4][2];
#pragma unroll
    for (int nt = 0; nt < 4; ++nt)
#pragma unroll
        for (int kh = 0; kh < 2; ++kh)
            bfr[nt][kh] = *(const frag_ab*)(Wb + (nt * 16 + ln) * 64 + kh * 32 + q * 8);
    const int nstrips = N_NODES_C / 16;
    for (int s = wave; s < nstrips; s += nwaves) {
        int r0 = s * 16;
        frag_ab a0 = *(const frag_ab*)(Xb + (size_t)(r0 + ln) * 64 + q * 8);
        frag_ab a1 = *(const frag_ab*)(Xb + (size_t)(r0 + ln) * 64 + 32 + q * 8);
        f32x4 acc[4];
#pragma unroll
        for (int nt = 0; nt < 4; ++nt) {
            acc[nt] = (f32x4){0.f, 0.f, 0.f, 0.f};
            acc[nt] = __builtin_amdgcn_mfma_f32_16x16x32_bf16(a0, bfr[nt][0], acc[nt], 0, 0, 0);
            acc[nt] = __builtin_amdgcn_mfma_f32_16x16x32_bf16(a1, bfr[nt][1], acc[nt], 0, 0, 0);
        }
        float di[4];
#pragma unroll
        for (int reg = 0; reg < 4; ++reg)
            di[reg] = rsqrtf((float)(cnt[r0 + q * 4 + reg] + 1));
#pragma unroll
        for (int nt = 0; nt < 4; ++nt)
#pragma unroll
            for (int reg = 0; reg < 4; ++reg)
                T[(size_t)(r0 + q * 4 + reg) * 64 + nt * 16 + ln] =
                    f2bf(acc[nt][reg] * di[reg]);
    }
}

// ------------------- gather: CSR, 4 rows / load, zero-row padding ---------
template <bool POOL>
__device__ __forceinline__ void gather_body(
        const u16* __restrict__ T, const int* __restrict__ col,
        const int* __restrict__ cnt, const int* __restrict__ start,
        const float* __restrict__ b, const float* __restrict__ g,
        const float* __restrict__ be, const float* __restrict__ m,
        const float* __restrict__ v, const int* __restrict__ batch,
        u16* __restrict__ Ab, float* __restrict__ pooled) {
    const int ZROW = N_NODES_C;
    int lane = threadIdx.x & 63;
    int h = lane >> 4, c = lane & 15;
    int cbase = c << 2;
    int wave = blockIdx.x * 4 + (threadIdx.x >> 6);
    int nwaves = gridDim.x * 4;
    float scv[4], c0v[4];
#pragma unroll
    for (int i = 0; i < 4; ++i) {
        float sci = g[cbase + i] * rsqrtf(v[cbase + i] + BN_EPS_C);
        scv[i] = sci;
        c0v[i] = (b[cbase + i] - m[cbase + i]) * sci + be[cbase + i];
    }
    const int chunk = (N_NODES_C + nwaves - 1) / nwaves;
    int p0 = wave * chunk;
    int p1 = p0 + chunk; if (p1 > N_NODES_C) p1 = N_NODES_C;
    if (p0 >= p1) return;

    float psum = 0.f; int curg = -1;

    // pipeline prologue: meta for p0, p0+1; col vector for p0
    int d0 = cnt[p0];
    int s0 = start[p0];
    int d1 = 0, s1 = 0;
    if (p0 + 1 < p1) { d1 = cnt[p0 + 1]; s1 = start[p0 + 1]; }
    int cv0 = col[(size_t)(u32)s0 + lane];

    for (int p = p0; p < p1; ++p) {
        int deg = __builtin_amdgcn_readfirstlane(d0);
        int cvR = cv0;
        if (p + 1 < p1) {  // rotate pipeline: col for p+1, meta for p+2
            cv0 = col[(size_t)(u32)s1 + lane];
            d0 = d1;
            if (p + 2 < p1) { d1 = cnt[p + 2]; s1 = start[p + 2]; }
        }
        if (deg > 63) deg = 63;
        // clean index vector: [neighbors | self | ZROW pad...]
        int cv = (lane < deg) ? cvR : ((lane == deg) ? p : ZROW);
        int iters = (deg + 4) >> 2;  // ceil((deg+1)/4), slots incl. self
        float a0 = 0.f, a1 = 0.f, a2 = 0.f, a3 = 0.f;
        int sl = h;
        int j = 0;
        for (; j + 2 <= iters; j += 2) {
            int i0 = __shfl(cv, sl);
            int i1 = __shfl(cv, sl + 4);
            uint2 t0 = *(const uint2*)(T + (((size_t)(u32)i0) << 6) + (c << 2));
            uint2 t1 = *(const uint2*)(T + (((size_t)(u32)i1) << 6) + (c << 2));
            a0 += __uint_as_float(t0.x << 16); a1 += __uint_as_float(t0.x & 0xffff0000u);
            a2 += __uint_as_float(t0.y << 16); a3 += __uint_as_float(t0.y & 0xffff0000u);
            a0 += __uint_as_float(t1.x << 16); a1 += __uint_as_float(t1.x & 0xffff0000u);
            a2 += __uint_as_float(t1.y << 16); a3 += __uint_as_float(t1.y & 0xffff0000u);
            sl += 8;
        }
        if (j < iters) {
            int i0 = __shfl(cv, sl);
            uint2 t0 = *(const uint2*)(T + (((size_t)(u32)i0) << 6) + (c << 2));
            a0 += __uint_as_float(t0.x << 16); a1 += __uint_as_float(t0.x & 0xffff0000u);
            a2 += __uint_as_float(t0.y << 16); a3 += __uint_as_float(t0.y & 0xffff0000u);
        }
        // reduce across the 4 h-groups
        a0 += __shfl_xor(a0, 16); a0 += __shfl_xor(a0, 32);
        a1 += __shfl_xor(a1, 16); a1 += __shfl_xor(a1, 32);
        a2 += __shfl_xor(a2, 16); a2 += __shfl_xor(a2, 32);
        a3 += __shfl_xor(a3, 16); a3 += __shfl_xor(a3, 32);
        float dr = rsqrtf((float)(deg + 1));
        if (POOL) {
            float asel = (h & 2) ? ((h & 1) ? a3 : a2) : ((h & 1) ? a1 : a0);
            float scl  = (h & 2) ? ((h & 1) ? scv[3] : scv[2]) : ((h & 1) ? scv[1] : scv[0]);
            float c0l  = (h & 2) ? ((h & 1) ? c0v[3] : c0v[2]) : ((h & 1) ? c0v[1] : c0v[0]);
            float vh = fmaxf(fmaf(asel * dr, scl, c0l), 0.f);
            int gg = batch[p];
            if (gg != curg) {
                if (curg >= 0) atomicAdd(&pooled[curg * 64 + cbase + h], psum);
                curg = gg; psum = 0.f;
            }
            psum += vh;
        } else {
            float v0 = fmaxf(fmaf(a0 * dr, scv[0], c0v[0]), 0.f);
            float v1 = fmaxf(fmaf(a1 * dr, scv[1], c0v[1]), 0.f);
            float v2 = fmaxf(fmaf(a2 * dr, scv[2], c0v[2]), 0.f);
            float v3 = fmaxf(fmaf(a3 * dr, scv[3], c0v[3]), 0.f);
            if (h == 0) {
                u32 w0 = (u32)f2bf(v0) | ((u32)f2bf(v1) << 16);
                u32 w1 = (u32)f2bf(v2) | ((u32)f2bf(v3) << 16);
                *(uint2*)(Ab + (((size_t)(u32)p) << 6) + (c << 2)) = make_uint2(w0, w1);
            }
        }
    }
    if (POOL && curg >= 0) atomicAdd(&pooled[curg * 64 + cbase + h], psum);
}

__global__ void __launch_bounds__(256) k_gather1(
        const u16* __restrict__ T, const int* __restrict__ col,
        const int* __restrict__ cnt, const int* __restrict__ start,
        const float* __restrict__ b, const float* __restrict__ g,
        const float* __restrict__ be, const float* __restrict__ m,
        const float* __restrict__ v, u16* __restrict__ Ab) {
    gather_body<false>(T, col, cnt, start, b, g, be, m, v, nullptr, Ab, nullptr);
}

__global__ void __launch_bounds__(256) k_gather2(
        const u16* __restrict__ T, const int* __restrict__ col,
        const int* __restrict__ cnt, const int* __restrict__ start,
        const float* __restrict__ b, const float* __restrict__ g,
        const float* __restrict__ be, const float* __restrict__ m,
        const float* __restrict__ v, const int* __restrict__ batch,
        float* __restrict__ pooled) {
    gather_body<true>(T, col, cnt, start, b, g, be, m, v, batch, nullptr, pooled);
}

// ----------------------------- classifier --------------------------------
__global__ void k_final(const float* __restrict__ pooled, const int* __restrict__ batch,
                        const float* __restrict__ Wc, const float* __restrict__ bc,
                        float* __restrict__ out) {
    __shared__ float sp[64 * 65];
    __shared__ int sub[64];
    int t = threadIdx.x;  // 256 threads
    for (int i = t; i < 4096; i += 256) sp[(i >> 6) * 65 + (i & 63)] = pooled[i];
    if (t < 64) {
        int lo = 0, hi = N_NODES_C;
        while (lo < hi) { int mid = (lo + hi) >> 1; if (batch[mid] > t) hi = mid; else lo = mid + 1; }
        sub[t] = lo;  // first index with batch > t
    }
    __syncthreads();
    if (t < 64) {
        int gi = t;
        int lb = gi ? sub[gi - 1] : 0;
        int cntg = sub[gi] - lb;
        float inv = 1.0f / fmaxf((float)cntg, 1.0f);
        float a0 = 0.f, a1 = 0.f;
#pragma unroll 8
        for (int f = 0; f < 64; ++f) {
            float p = sp[gi * 65 + f];
            a0 = fmaf(p, Wc[f * 2 + 0], a0);
            a1 = fmaf(p, Wc[f * 2 + 1], a1);
        }
        out[gi * 2 + 0] = a0 * inv + bc[0];
        out[gi * 2 + 1] = a1 * inv + bc[1];
    }
}

extern "C" void kernel_launch(void* const* d_in, const int* in_sizes, int n_in,
                              void* d_out, int out_size, void* d_ws, size_t ws_size,
                              hipStream_t stream) {
    const float* x    = (const float*)d_in[0];
    const int*   ei   = (const int*)d_in[1];
    const int*   batch= (const int*)d_in[2];
    const float* W1 = (const float*)d_in[3];
    const float* b1 = (const float*)d_in[4];
    const float* g1 = (const float*)d_in[5];
    const float* be1= (const float*)d_in[6];
    const float* m1 = (const float*)d_in[7];
    const float* v1 = (const float*)d_in[8];
    const float* W2 = (const float*)d_in[9];
    const float* b2 = (const float*)d_in[10];
    const float* g2 = (const float*)d_in[11];
    const float* be2= (const float*)d_in[12];
    const float* m2 = (const float*)d_in[13];
    const float* v2 = (const float*)d_in[14];
    const float* Wc = (const float*)d_in[15];
    const float* bc = (const float*)d_in[16];
    float* out = (float*)d_out;

    char* ws = (char*)d_ws;
    size_t off = 0;
    auto alloc = [&](size_t bytes) {
        size_t o = off;
        off = (off + bytes + 511) & ~(size_t)511;
        return o;
    };
    size_t o_cntp  = alloc((size_t)SH_N * PLANE_W * 4);    // 1.6 MB shard counters
    size_t o_pool  = alloc((size_t)NUM_GRAPHS_C * D_C * 4);
    size_t zero_bytes = off;  // [cntp | pooled] zeroed each call
    size_t o_cnt   = alloc((size_t)N_NODES_C * 4);
    size_t o_start = alloc((size_t)(N_NODES_C + 64) * 4);  // CSR row starts
    size_t o_stsh  = alloc((size_t)SH_N * N_NODES_C * 4);  // 6.4 MB shard starts
    size_t o_pos8  = alloc((size_t)N_EDGES_C);             // u8 per-edge slot
    size_t o_col   = alloc((size_t)(N_EDGES_C + 64) * 4);  // CSR 4.8 MB (+pad)
    size_t o_bsum  = alloc(512 * 4);
    size_t o_xb    = alloc((size_t)N_NODES_C * D_C * 2);
    size_t o_wb1   = alloc(4096 * 2);
    size_t o_wb2   = alloc(4096 * 2);
    size_t o_t     = alloc((size_t)(N_NODES_C + 1) * D_C * 2);  // +1: zero row
    size_t o_ab    = alloc((size_t)N_NODES_C * D_C * 2);  // bf16 activations
    (void)ws_size; (void)in_sizes; (void)n_in; (void)out_size;

    u32*   cntp   = (u32*)(ws + o_cntp);
    float* pooled = (float*)(ws + o_pool);
    int*   cnt    = (int*)(ws + o_cnt);
    int*   startp = (int*)(ws + o_start);
    int*   stsh   = (int*)(ws + o_stsh);
    u8*    pos8   = (u8*)(ws + o_pos8);
    int*   col    = (int*)(ws + o_col);
    int*   bsum   = (int*)(ws + o_bsum);
    u16*   Xb     = (u16*)(ws + o_xb);
    u16*   Wb1    = (u16*)(ws + o_wb1);
    u16*   Wb2    = (u16*)(ws + o_wb2);
    u16*   T      = (u16*)(ws + o_t);
    u16*   Ab     = (u16*)(ws + o_ab);

    const int* srcp = ei;
    const int* dstp = ei + N_EDGES_C;

    hipMemsetAsync(ws, 0, zero_bytes, stream);

    int pblocks = (N_NODES_C * D_C / 4 + 255) / 256;  // 6250
    int cblocks = 1172;   // 300032 threads: 1 quad each
    int sblocks = 2048;   // 256 chunks x 8 XCD-swizzled ranges
    int gblocks = 2048;   // 8192 persistent waves
    int mblocks = 1563;   // 6252 waves: one 16-row strip each
    k_prep<<<pblocks, 256, 0, stream>>>(x, W1, W2, Xb, Wb1, Wb2, T);
    k_count<<<cblocks, 256, 0, stream>>>(dstp, cntp, pos8);
    k_scan1<<<SCAN_B, 256, 0, stream>>>(cntp, cnt, startp, bsum);
    k_scan2<<<1, 512, 0, stream>>>(bsum);
    k_scan3<<<SCAN_B, 256, 0, stream>>>(startp, bsum, cntp, stsh);
    k_place<<<sblocks, 256, 0, stream>>>(srcp, dstp, pos8, stsh, col);

    k_gemm_mfma<<<mblocks, 256, 0, stream>>>(Xb, Wb1, cnt, T);
    k_gather1<<<gblocks, 256, 0, stream>>>(T, col, cnt, startp, b1, g1, be1, m1, v1, Ab);
    k_gemm_mfma<<<mblocks, 256, 0, stream>>>(Ab, Wb2, cnt, T);
    k_gather2<<<gblocks, 256, 0, stream>>>(T, col, cnt, startp, b2, g2, be2, m2, v2,
                                           batch, pooled);
    k_final<<<1, 256, 0, stream>>>(pooled, batch, Wc, bc, out);
}

// Round 5
// 235.015 us; speedup vs baseline: 1.1769x; 1.1769x over previous
//
#include <hip/hip_runtime.h>

#define N_NODES_C 100000
#define N_EDGES_C 1200000
#define NQUADS_C 300000
#define NUM_GRAPHS_C 64
#define D_C 64
#define BN_EPS_C 1e-5f

#define BU_SH 7                 // 128 nodes per bucket
#define NB_C 782                // ceil(100000/128)
#define PART_B 512              // partition blocks (= 64 lanes x 8 in k_pscan)
#define QPB 586                 // ceil(300000/512) quads per partition block

typedef unsigned short u16;
typedef unsigned int u32;

using frag_ab = __attribute__((ext_vector_type(8))) short;  // 8 bf16 (4 VGPRs)
using f32x4   = __attribute__((ext_vector_type(4))) float;

__device__ __forceinline__ u16 f2bf(float f) {  // RTNE
    u32 x = __float_as_uint(f);
    x += 0x7fffu + ((x >> 16) & 1u);
    return (u16)(x >> 16);
}
__device__ __forceinline__ float bf2f(u16 u) {
    return __uint_as_float(((u32)u) << 16);
}

// ------------- prep: x->bf16, W->bf16[n][k], zero row ---------------------
__global__ void k_prep(const float* __restrict__ x,
                       const float* __restrict__ W1, const float* __restrict__ W2,
                       u16* __restrict__ Xb, u16* __restrict__ Wb1,
                       u16* __restrict__ Wb2, u16* __restrict__ T) {
    int i = blockIdx.x * 256 + threadIdx.x;
    int base = i * 4;
    if (base < N_NODES_C * D_C) {
        float4 f = *(const float4*)(x + base);
        ushort4 o;
        o.x = f2bf(f.x); o.y = f2bf(f.y); o.z = f2bf(f.z); o.w = f2bf(f.w);
        *(ushort4*)(Xb + base) = o;
    }
    if (i < 4096) {  // W[k][n] -> Wb[n][k]
        int n = i >> 6, k = i & 63;
        Wb1[i] = f2bf(W1[k * 64 + n]);
        Wb2[i] = f2bf(W2[k * 64 + n]);
    }
    if (i < 64) T[(size_t)N_NODES_C * 64 + i] = 0;  // zero row (survives gemms)
}

// ============ atomic-free CSR build (radix partition, LDS ranks) ==========
// R2/R3/R4 all hit a ~50 us floor for 1.2M device-scope atomics (~25 G/s
// with return) regardless of line sharding => eliminate global atomics.
// Node-buckets of 128; per-(block,bucket) counts; deterministic slots.

// ---- A: per-block bucket histogram (identical chunking to k_part) --------
__global__ void __launch_bounds__(256) k_hist(const int* __restrict__ dst,
                                              u32* __restrict__ hist_all) {
    __shared__ u32 hist[NB_C];
    int b = blockIdx.x, t = threadIdx.x;
    for (int i = t; i < NB_C; i += 256) hist[i] = 0;
    __syncthreads();
    int qlo = b * QPB, qhi = qlo + QPB; if (qhi > NQUADS_C) qhi = NQUADS_C;
    const int4* d4 = (const int4*)dst;
    for (int i = qlo + t; i < qhi; i += 256) {
        int4 d = d4[i];
        atomicAdd(&hist[d.x >> BU_SH], 1u);
        atomicAdd(&hist[d.y >> BU_SH], 1u);
        atomicAdd(&hist[d.z >> BU_SH], 1u);
        atomicAdd(&hist[d.w >> BU_SH], 1u);
    }
    __syncthreads();
    for (int i = t; i < NB_C; i += 256) hist_all[(size_t)b * NB_C + i] = hist[i];
}

// ---- B: per-bucket exclusive scan along the 512 blocks (wave/bucket) -----
__global__ void __launch_bounds__(256) k_pscan(const u32* __restrict__ hist_all,
                                               u32* __restrict__ partLocal,
                                               u32* __restrict__ bucketTotal) {
    int wv = blockIdx.x * 4 + (threadIdx.x >> 6);
    int l = threadIdx.x & 63;
    if (wv >= NB_C) return;
    u32 v[8];
#pragma unroll
    for (int j = 0; j < 8; ++j) v[j] = hist_all[(size_t)(l * 8 + j) * NB_C + wv];
    u32 s = 0;
#pragma unroll
    for (int j = 0; j < 8; ++j) { u32 tv = v[j]; v[j] = s; s += tv; }
    u32 run = s;  // wave exclusive scan of per-lane sums
#pragma unroll
    for (int off = 1; off < 64; off <<= 1) {
        u32 y = __shfl_up(run, off);
        if (l >= off) run += y;
    }
    u32 excl = run - s;
#pragma unroll
    for (int j = 0; j < 8; ++j)
        partLocal[(size_t)(l * 8 + j) * NB_C + wv] = excl + v[j];
    if (l == 63) bucketTotal[wv] = run;  // inclusive total
}

// ---- C: scan bucket totals -> bucketStart --------------------------------
__global__ void __launch_bounds__(1024) k_bscan(const u32* __restrict__ bucketTotal,
                                                u32* __restrict__ bucketStart) {
    __shared__ u32 sh[1024];
    int t = threadIdx.x;
    u32 c = (t < NB_C) ? bucketTotal[t] : 0;
    u32 val = c;
    sh[t] = val;
    __syncthreads();
#pragma unroll
    for (int off = 1; off < 1024; off <<= 1) {
        u32 y = (t >= off) ? sh[t - off] : 0;
        __syncthreads();
        val += y;
        sh[t] = val;
        __syncthreads();
    }
    if (t < NB_C) bucketStart[t] = val - c;
    if (t == 0) bucketStart[NB_C] = N_EDGES_C;
}

// ---- D: partition scatter — LDS ranks, deterministic slots, no atomics ---
__global__ void __launch_bounds__(256) k_part(const int* __restrict__ src,
                                              const int* __restrict__ dst,
                                              const u32* __restrict__ partLocal,
                                              const u32* __restrict__ bucketStart,
                                              uint2* __restrict__ pairs) {
    __shared__ u32 baseLDS[NB_C];
    __shared__ u32 rank[NB_C];
    int b = blockIdx.x, t = threadIdx.x;
    for (int i = t; i < NB_C; i += 256) {
        baseLDS[i] = bucketStart[i] + partLocal[(size_t)b * NB_C + i];
        rank[i] = 0;
    }
    __syncthreads();
    int qlo = b * QPB, qhi = qlo + QPB; if (qhi > NQUADS_C) qhi = NQUADS_C;
    const int4* d4 = (const int4*)dst;
    const int4* s4 = (const int4*)src;
    for (int i = qlo + t; i < qhi; i += 256) {
        int4 d = d4[i];
        int4 s = s4[i];
        int dd[4] = {d.x, d.y, d.z, d.w};
        int ss[4] = {s.x, s.y, s.z, s.w};
#pragma unroll
        for (int k = 0; k < 4; ++k) {
            int bu = dd[k] >> BU_SH;
            u32 r = atomicAdd(&rank[bu], 1u);  // LDS atomic
            pairs[baseLDS[bu] + r] = make_uint2((u32)ss[k], (u32)dd[k]);
        }
    }
}

// ---- E: per-bucket CSR finalize: cnt, start, col (all LDS-local) ---------
__global__ void __launch_bounds__(256) k_csr(const uint2* __restrict__ pairs,
                                             const u32* __restrict__ bucketStart,
                                             int* __restrict__ cnt,
                                             int* __restrict__ start,
                                             int* __restrict__ col) {
    __shared__ u32 cl[128];
    __shared__ u32 sl[128];
    __shared__ u32 rk[128];
    __shared__ int sh[256];
    int bu = blockIdx.x, t = threadIdx.x;
    int n0 = bu << BU_SH;
    u32 seg0 = bucketStart[bu], seg1 = bucketStart[bu + 1];
    if (t < 128) { cl[t] = 0; rk[t] = 0; }
    __syncthreads();
    for (u32 i = seg0 + t; i < seg1; i += 256)
        atomicAdd(&cl[pairs[i].y - n0], 1u);  // LDS atomic
    __syncthreads();
    int c = (t < 128) ? (int)cl[t] : 0;
    int val = c;
    sh[t] = val;
    __syncthreads();
#pragma unroll
    for (int off = 1; off < 128; off <<= 1) {
        int y = (t >= off) ? sh[t - off] : 0;
        __syncthreads();
        val += y;
        sh[t] = val;
        __syncthreads();
    }
    if (t < 128) {
        int node = n0 + t;
        u32 st = seg0 + (u32)(val - c);
        sl[t] = st;
        if (node < N_NODES_C) { cnt[node] = c; start[node] = (int)st; }
    }
    __syncthreads();
    for (u32 i = seg0 + t; i < seg1; i += 256) {
        uint2 pr = pairs[i];
        u32 loc = pr.y - n0;
        u32 r = atomicAdd(&rk[loc], 1u);  // LDS atomic
        col[sl[loc] + r] = (int)pr.x;
    }
}

// ------------------- GEMM via MFMA 16x16x32 bf16 --------------------------
__global__ void __launch_bounds__(256) k_gemm_mfma(
        const u16* __restrict__ Xb, const u16* __restrict__ Wb,
        const int* __restrict__ cnt, u16* __restrict__ T) {
    int lane = threadIdx.x & 63;
    int q = lane >> 4, ln = lane & 15;
    int wave = blockIdx.x * 4 + (threadIdx.x >> 6);
    int nwaves = gridDim.x * 4;
    frag_ab bfr[4][2];
#pragma unroll
    for (int nt = 0; nt < 4; ++nt)
#pragma unroll
        for (int kh = 0; kh < 2; ++kh)
            bfr[nt][kh] = *(const frag_ab*)(Wb + (nt * 16 + ln) * 64 + kh * 32 + q * 8);
    const int nstrips = N_NODES_C / 16;
    for (int s = wave; s < nstrips; s += nwaves) {
        int r0 = s * 16;
        frag_ab a0 = *(const frag_ab*)(Xb + (size_t)(r0 + ln) * 64 + q * 8);
        frag_ab a1 = *(const frag_ab*)(Xb + (size_t)(r0 + ln) * 64 + 32 + q * 8);
        f32x4 acc[4];
#pragma unroll
        for (int nt = 0; nt < 4; ++nt) {
            acc[nt] = (f32x4){0.f, 0.f, 0.f, 0.f};
            acc[nt] = __builtin_amdgcn_mfma_f32_16x16x32_bf16(a0, bfr[nt][0], acc[nt], 0, 0, 0);
            acc[nt] = __builtin_amdgcn_mfma_f32_16x16x32_bf16(a1, bfr[nt][1], acc[nt], 0, 0, 0);
        }
        float di[4];
#pragma unroll
        for (int reg = 0; reg < 4; ++reg)
            di[reg] = rsqrtf((float)(cnt[r0 + q * 4 + reg] + 1));
#pragma unroll
        for (int nt = 0; nt < 4; ++nt)
#pragma unroll
            for (int reg = 0; reg < 4; ++reg)
                T[(size_t)(r0 + q * 4 + reg) * 64 + nt * 16 + ln] =
                    f2bf(acc[nt][reg] * di[reg]);
    }
}

// ------------------- gather: CSR, 4 rows / load, zero-row padding ---------
template <bool POOL>
__device__ __forceinline__ void gather_body(
        const u16* __restrict__ T, const int* __restrict__ col,
        const int* __restrict__ cnt, const int* __restrict__ start,
        const float* __restrict__ b, const float* __restrict__ g,
        const float* __restrict__ be, const float* __restrict__ m,
        const float* __restrict__ v, const int* __restrict__ batch,
        u16* __restrict__ Ab, float* __restrict__ pooled) {
    const int ZROW = N_NODES_C;
    int lane = threadIdx.x & 63;
    int h = lane >> 4, c = lane & 15;
    int cbase = c << 2;
    int wave = blockIdx.x * 4 + (threadIdx.x >> 6);
    int nwaves = gridDim.x * 4;
    float scv[4], c0v[4];
#pragma unroll
    for (int i = 0; i < 4; ++i) {
        float sci = g[cbase + i] * rsqrtf(v[cbase + i] + BN_EPS_C);
        scv[i] = sci;
        c0v[i] = (b[cbase + i] - m[cbase + i]) * sci + be[cbase + i];
    }
    const int chunk = (N_NODES_C + nwaves - 1) / nwaves;
    int p0 = wave * chunk;
    int p1 = p0 + chunk; if (p1 > N_NODES_C) p1 = N_NODES_C;
    if (p0 >= p1) return;

    float psum = 0.f; int curg = -1;

    // pipeline prologue: meta for p0, p0+1; col vector for p0
    int d0 = cnt[p0];
    int s0 = start[p0];
    int d1 = 0, s1 = 0;
    if (p0 + 1 < p1) { d1 = cnt[p0 + 1]; s1 = start[p0 + 1]; }
    int cv0 = col[(size_t)(u32)s0 + lane];

    for (int p = p0; p < p1; ++p) {
        int deg = __builtin_amdgcn_readfirstlane(d0);
        int cvR = cv0;
        if (p + 1 < p1) {  // rotate pipeline: col for p+1, meta for p+2
            cv0 = col[(size_t)(u32)s1 + lane];
            d0 = d1;
            if (p + 2 < p1) { d1 = cnt[p + 2]; s1 = start[p + 2]; }
        }
        if (deg > 63) deg = 63;
        // clean index vector: [neighbors | self | ZROW pad...]
        int cv = (lane < deg) ? cvR : ((lane == deg) ? p : ZROW);
        int iters = (deg + 4) >> 2;  // ceil((deg+1)/4), slots incl. self
        float a0 = 0.f, a1 = 0.f, a2 = 0.f, a3 = 0.f;
        int sl = h;
        int j = 0;
        for (; j + 2 <= iters; j += 2) {
            int i0 = __shfl(cv, sl);
            int i1 = __shfl(cv, sl + 4);
            uint2 t0 = *(const uint2*)(T + (((size_t)(u32)i0) << 6) + (c << 2));
            uint2 t1 = *(const uint2*)(T + (((size_t)(u32)i1) << 6) + (c << 2));
            a0 += __uint_as_float(t0.x << 16); a1 += __uint_as_float(t0.x & 0xffff0000u);
            a2 += __uint_as_float(t0.y << 16); a3 += __uint_as_float(t0.y & 0xffff0000u);
            a0 += __uint_as_float(t1.x << 16); a1 += __uint_as_float(t1.x & 0xffff0000u);
            a2 += __uint_as_float(t1.y << 16); a3 += __uint_as_float(t1.y & 0xffff0000u);
            sl += 8;
        }
        if (j < iters) {
            int i0 = __shfl(cv, sl);
            uint2 t0 = *(const uint2*)(T + (((size_t)(u32)i0) << 6) + (c << 2));
            a0 += __uint_as_float(t0.x << 16); a1 += __uint_as_float(t0.x & 0xffff0000u);
            a2 += __uint_as_float(t0.y << 16); a3 += __uint_as_float(t0.y & 0xffff0000u);
        }
        // reduce across the 4 h-groups
        a0 += __shfl_xor(a0, 16); a0 += __shfl_xor(a0, 32);
        a1 += __shfl_xor(a1, 16); a1 += __shfl_xor(a1, 32);
        a2 += __shfl_xor(a2, 16); a2 += __shfl_xor(a2, 32);
        a3 += __shfl_xor(a3, 16); a3 += __shfl_xor(a3, 32);
        float dr = rsqrtf((float)(deg + 1));
        if (POOL) {
            float asel = (h & 2) ? ((h & 1) ? a3 : a2) : ((h & 1) ? a1 : a0);
            float scl  = (h & 2) ? ((h & 1) ? scv[3] : scv[2]) : ((h & 1) ? scv[1] : scv[0]);
            float c0l  = (h & 2) ? ((h & 1) ? c0v[3] : c0v[2]) : ((h & 1) ? c0v[1] : c0v[0]);
            float vh = fmaxf(fmaf(asel * dr, scl, c0l), 0.f);
            int gg = batch[p];
            if (gg != curg) {
                if (curg >= 0) atomicAdd(&pooled[curg * 64 + cbase + h], psum);
                curg = gg; psum = 0.f;
            }
            psum += vh;
        } else {
            float v0 = fmaxf(fmaf(a0 * dr, scv[0], c0v[0]), 0.f);
            float v1 = fmaxf(fmaf(a1 * dr, scv[1], c0v[1]), 0.f);
            float v2 = fmaxf(fmaf(a2 * dr, scv[2], c0v[2]), 0.f);
            float v3 = fmaxf(fmaf(a3 * dr, scv[3], c0v[3]), 0.f);
            if (h == 0) {
                u32 w0 = (u32)f2bf(v0) | ((u32)f2bf(v1) << 16);
                u32 w1 = (u32)f2bf(v2) | ((u32)f2bf(v3) << 16);
                *(uint2*)(Ab + (((size_t)(u32)p) << 6) + (c << 2)) = make_uint2(w0, w1);
            }
        }
    }
    if (POOL && curg >= 0) atomicAdd(&pooled[curg * 64 + cbase + h], psum);
}

__global__ void __launch_bounds__(256) k_gather1(
        const u16* __restrict__ T, const int* __restrict__ col,
        const int* __restrict__ cnt, const int* __restrict__ start,
        const float* __restrict__ b, const float* __restrict__ g,
        const float* __restrict__ be, const float* __restrict__ m,
        const float* __restrict__ v, u16* __restrict__ Ab) {
    gather_body<false>(T, col, cnt, start, b, g, be, m, v, nullptr, Ab, nullptr);
}

__global__ void __launch_bounds__(256) k_gather2(
        const u16* __restrict__ T, const int* __restrict__ col,
        const int* __restrict__ cnt, const int* __restrict__ start,
        const float* __restrict__ b, const float* __restrict__ g,
        const float* __restrict__ be, const float* __restrict__ m,
        const float* __restrict__ v, const int* __restrict__ batch,
        float* __restrict__ pooled) {
    gather_body<true>(T, col, cnt, start, b, g, be, m, v, batch, nullptr, pooled);
}

// ----------------------------- classifier --------------------------------
__global__ void k_final(const float* __restrict__ pooled, const int* __restrict__ batch,
                        const float* __restrict__ Wc, const float* __restrict__ bc,
                        float* __restrict__ out) {
    __shared__ float sp[64 * 65];
    __shared__ int sub[64];
    int t = threadIdx.x;  // 256 threads
    for (int i = t; i < 4096; i += 256) sp[(i >> 6) * 65 + (i & 63)] = pooled[i];
    if (t < 64) {
        int lo = 0, hi = N_NODES_C;
        while (lo < hi) { int mid = (lo + hi) >> 1; if (batch[mid] > t) hi = mid; else lo = mid + 1; }
        sub[t] = lo;  // first index with batch > t
    }
    __syncthreads();
    if (t < 64) {
        int gi = t;
        int lb = gi ? sub[gi - 1] : 0;
        int cntg = sub[gi] - lb;
        float inv = 1.0f / fmaxf((float)cntg, 1.0f);
        float a0 = 0.f, a1 = 0.f;
#pragma unroll 8
        for (int f = 0; f < 64; ++f) {
            float p = sp[gi * 65 + f];
            a0 = fmaf(p, Wc[f * 2 + 0], a0);
            a1 = fmaf(p, Wc[f * 2 + 1], a1);
        }
        out[gi * 2 + 0] = a0 * inv + bc[0];
        out[gi * 2 + 1] = a1 * inv + bc[1];
    }
}

extern "C" void kernel_launch(void* const* d_in, const int* in_sizes, int n_in,
                              void* d_out, int out_size, void* d_ws, size_t ws_size,
                              hipStream_t stream) {
    const float* x    = (const float*)d_in[0];
    const int*   ei   = (const int*)d_in[1];
    const int*   batch= (const int*)d_in[2];
    const float* W1 = (const float*)d_in[3];
    const float* b1 = (const float*)d_in[4];
    const float* g1 = (const float*)d_in[5];
    const float* be1= (const float*)d_in[6];
    const float* m1 = (const float*)d_in[7];
    const float* v1 = (const float*)d_in[8];
    const float* W2 = (const float*)d_in[9];
    const float* b2 = (const float*)d_in[10];
    const float* g2 = (const float*)d_in[11];
    const float* be2= (const float*)d_in[12];
    const float* m2 = (const float*)d_in[13];
    const float* v2 = (const float*)d_in[14];
    const float* Wc = (const float*)d_in[15];
    const float* bc = (const float*)d_in[16];
    float* out = (float*)d_out;

    char* ws = (char*)d_ws;
    size_t off = 0;
    auto alloc = [&](size_t bytes) {
        size_t o = off;
        off = (off + bytes + 511) & ~(size_t)511;
        return o;
    };
    size_t o_pool  = alloc((size_t)NUM_GRAPHS_C * D_C * 4);
    size_t zero_bytes = off;  // only pooled zeroed each call
    size_t o_hist  = alloc((size_t)PART_B * NB_C * 4);     // 1.6 MB
    size_t o_ploc  = alloc((size_t)PART_B * NB_C * 4);     // 1.6 MB
    size_t o_btot  = alloc((size_t)NB_C * 4);
    size_t o_bst   = alloc((size_t)(NB_C + 2) * 4);
    size_t o_pairs = alloc((size_t)N_EDGES_C * 8);         // 9.6 MB (src,dst)
    size_t o_cnt   = alloc((size_t)N_NODES_C * 4);
    size_t o_start = alloc((size_t)(N_NODES_C + 64) * 4);
    size_t o_col   = alloc((size_t)(N_EDGES_C + 64) * 4);  // CSR 4.8 MB (+pad)
    size_t o_xb    = alloc((size_t)N_NODES_C * D_C * 2);
    size_t o_wb1   = alloc(4096 * 2);
    size_t o_wb2   = alloc(4096 * 2);
    size_t o_t     = alloc((size_t)(N_NODES_C + 1) * D_C * 2);  // +1: zero row
    size_t o_ab    = alloc((size_t)N_NODES_C * D_C * 2);
    (void)ws_size; (void)in_sizes; (void)n_in; (void)out_size;

    float* pooled = (float*)(ws + o_pool);
    u32*   hist   = (u32*)(ws + o_hist);
    u32*   ploc   = (u32*)(ws + o_ploc);
    u32*   btot   = (u32*)(ws + o_btot);
    u32*   bst    = (u32*)(ws + o_bst);
    uint2* pairs  = (uint2*)(ws + o_pairs);
    int*   cnt    = (int*)(ws + o_cnt);
    int*   startp = (int*)(ws + o_start);
    int*   col    = (int*)(ws + o_col);
    u16*   Xb     = (u16*)(ws + o_xb);
    u16*   Wb1    = (u16*)(ws + o_wb1);
    u16*   Wb2    = (u16*)(ws + o_wb2);
    u16*   T      = (u16*)(ws + o_t);
    u16*   Ab     = (u16*)(ws + o_ab);

    const int* srcp = ei;
    const int* dstp = ei + N_EDGES_C;

    hipMemsetAsync(ws, 0, zero_bytes, stream);

    int pblocks = (N_NODES_C * D_C / 4 + 255) / 256;  // 6250
    int gblocks = 2048;   // 8192 persistent waves
    int mblocks = 1563;   // 6252 waves: one 16-row strip each
    k_prep<<<pblocks, 256, 0, stream>>>(x, W1, W2, Xb, Wb1, Wb2, T);
    k_hist<<<PART_B, 256, 0, stream>>>(dstp, hist);
    k_pscan<<<(NB_C + 3) / 4, 256, 0, stream>>>(hist, ploc, btot);
    k_bscan<<<1, 1024, 0, stream>>>(btot, bst);
    k_part<<<PART_B, 256, 0, stream>>>(srcp, dstp, ploc, bst, pairs);
    k_csr<<<NB_C, 256, 0, stream>>>(pairs, bst, cnt, startp, col);

    k_gemm_mfma<<<mblocks, 256, 0, stream>>>(Xb, Wb1, cnt, T);
    k_gather1<<<gblocks, 256, 0, stream>>>(T, col, cnt, startp, b1, g1, be1, m1, v1, Ab);
    k_gemm_mfma<<<mblocks, 256, 0, stream>>>(Ab, Wb2, cnt, T);
    k_gather2<<<gblocks, 256, 0, stream>>>(T, col, cnt, startp, b2, g2, be2, m2, v2,
                                           batch, pooled);
    k_final<<<1, 256, 0, stream>>>(pooled, batch, Wc, bc, out);
}

// Round 6
// 217.029 us; speedup vs baseline: 1.2744x; 1.0829x over previous
//
#include <hip/hip_runtime.h>

#define N_NODES_C 100000
#define N_EDGES_C 1200000
#define NQUADS_C 300000
#define NUM_GRAPHS_C 64
#define D_C 64
#define BN_EPS_C 1e-5f

#define BU_SH 7                 // 128 nodes per bucket
#define NB_C 782                // ceil(100000/128)
#define PART_B 512              // partition blocks
#define QPB 586                 // ceil(300000/512) quads per partition block
#define NSTRIP_C 6250           // 100000/16

typedef unsigned short u16;
typedef unsigned int u32;

using frag_ab = __attribute__((ext_vector_type(8))) short;  // 8 bf16 (4 VGPRs)
using f32x4   = __attribute__((ext_vector_type(4))) float;

__device__ __forceinline__ u16 f2bf(float f) {  // RTNE
    u32 x = __float_as_uint(f);
    x += 0x7fffu + ((x >> 16) & 1u);
    return (u16)(x >> 16);
}
__device__ __forceinline__ float bf2f(u16 u) {
    return __uint_as_float(((u32)u) << 16);
}

// ------------- prepW: W1/W2 -> bf16 [n][k]; zero rows of T, T2 ------------
__global__ void k_prepW(const float* __restrict__ W1, const float* __restrict__ W2,
                        u16* __restrict__ Wb1, u16* __restrict__ Wb2,
                        u16* __restrict__ T, u16* __restrict__ T2) {
    int i = blockIdx.x * 256 + threadIdx.x;
    if (i < 4096) {  // W[k][n] -> Wb[n][k]
        int n = i >> 6, k = i & 63;
        Wb1[i] = f2bf(W1[k * 64 + n]);
        Wb2[i] = f2bf(W2[k * 64 + n]);
    }
    if (i < 64) {
        T[(size_t)N_NODES_C * 64 + i] = 0;   // zero rows (gather padding)
        T2[(size_t)N_NODES_C * 64 + i] = 0;
    }
}

// ============ atomic-free CSR build (radix partition, LDS ranks) ==========

// ---- A: per-block bucket histogram (identical chunking to k_part) --------
__global__ void __launch_bounds__(256) k_hist(const int* __restrict__ dst,
                                              u32* __restrict__ hist_all) {
    __shared__ u32 hist[NB_C];
    int b = blockIdx.x, t = threadIdx.x;
    for (int i = t; i < NB_C; i += 256) hist[i] = 0;
    __syncthreads();
    int qlo = b * QPB, qhi = qlo + QPB; if (qhi > NQUADS_C) qhi = NQUADS_C;
    const int4* d4 = (const int4*)dst;
    for (int i = qlo + t; i < qhi; i += 256) {
        int4 d = d4[i];
        atomicAdd(&hist[d.x >> BU_SH], 1u);
        atomicAdd(&hist[d.y >> BU_SH], 1u);
        atomicAdd(&hist[d.z >> BU_SH], 1u);
        atomicAdd(&hist[d.w >> BU_SH], 1u);
    }
    __syncthreads();
    for (int i = t; i < NB_C; i += 256) hist_all[(size_t)b * NB_C + i] = hist[i];
}

// ---- B: per-bucket exclusive scan along the 512 blocks (wave/bucket) -----
__global__ void __launch_bounds__(256) k_pscan(const u32* __restrict__ hist_all,
                                               u32* __restrict__ partLocal,
                                               u32* __restrict__ bucketTotal) {
    int wv = blockIdx.x * 4 + (threadIdx.x >> 6);
    int l = threadIdx.x & 63;
    if (wv >= NB_C) return;
    u32 v[8];
#pragma unroll
    for (int j = 0; j < 8; ++j) v[j] = hist_all[(size_t)(l * 8 + j) * NB_C + wv];
    u32 s = 0;
#pragma unroll
    for (int j = 0; j < 8; ++j) { u32 tv = v[j]; v[j] = s; s += tv; }
    u32 run = s;  // wave exclusive scan of per-lane sums
#pragma unroll
    for (int off = 1; off < 64; off <<= 1) {
        u32 y = __shfl_up(run, off);
        if (l >= off) run += y;
    }
    u32 excl = run - s;
#pragma unroll
    for (int j = 0; j < 8; ++j)
        partLocal[(size_t)(l * 8 + j) * NB_C + wv] = excl + v[j];
    if (l == 63) bucketTotal[wv] = run;  // inclusive total
}

// ---- C: scan bucket totals -> bucketStart --------------------------------
__global__ void __launch_bounds__(1024) k_bscan(const u32* __restrict__ bucketTotal,
                                                u32* __restrict__ bucketStart) {
    __shared__ u32 sh[1024];
    int t = threadIdx.x;
    u32 c = (t < NB_C) ? bucketTotal[t] : 0;
    u32 val = c;
    sh[t] = val;
    __syncthreads();
#pragma unroll
    for (int off = 1; off < 1024; off <<= 1) {
        u32 y = (t >= off) ? sh[t - off] : 0;
        __syncthreads();
        val += y;
        sh[t] = val;
        __syncthreads();
    }
    if (t < NB_C) bucketStart[t] = val - c;
    if (t == 0) bucketStart[NB_C] = N_EDGES_C;
}

// ---- D: partition scatter — LDS ranks, packed u32, XCD-clustered ---------
// lb remap: XCD x owns logical blocks [64x, 64x+63] (contiguous), so the
// ~12-24 B bucket segments of ADJACENT logical blocks (which share 64 B
// lines) are written by the SAME XCD's L2 instead of ping-ponging across 8.
// Entry packs src (17 bits) | in-bucket node (7 bits) -> 4.8 MB halved.
__global__ void __launch_bounds__(256) k_part(const int* __restrict__ src,
                                              const int* __restrict__ dst,
                                              const u32* __restrict__ partLocal,
                                              const u32* __restrict__ bucketStart,
                                              u32* __restrict__ pairs) {
    __shared__ u32 baseLDS[NB_C];
    __shared__ u32 rank[NB_C];
    int lb = ((blockIdx.x & 7) << 6) | (blockIdx.x >> 3);  // XCD-contiguous
    int t = threadIdx.x;
    for (int i = t; i < NB_C; i += 256) {
        baseLDS[i] = bucketStart[i] + partLocal[(size_t)lb * NB_C + i];
        rank[i] = 0;
    }
    __syncthreads();
    int qlo = lb * QPB, qhi = qlo + QPB; if (qhi > NQUADS_C) qhi = NQUADS_C;
    const int4* d4 = (const int4*)dst;
    const int4* s4 = (const int4*)src;
    for (int i = qlo + t; i < qhi; i += 256) {
        int4 d = d4[i];
        int4 s = s4[i];
        int dd[4] = {d.x, d.y, d.z, d.w};
        int ss[4] = {s.x, s.y, s.z, s.w};
#pragma unroll
        for (int k = 0; k < 4; ++k) {
            int bu = dd[k] >> BU_SH;
            u32 r = atomicAdd(&rank[bu], 1u);  // LDS atomic
            pairs[baseLDS[bu] + r] = (u32)ss[k] | ((u32)(dd[k] & 127) << 17);
        }
    }
}

// ---- E: per-bucket CSR finalize: cnt, start, col (all LDS-local) ---------
__global__ void __launch_bounds__(256) k_csr(const u32* __restrict__ pairs,
                                             const u32* __restrict__ bucketStart,
                                             int* __restrict__ cnt,
                                             int* __restrict__ start,
                                             int* __restrict__ col) {
    __shared__ u32 cl[128];
    __shared__ u32 sl[128];
    __shared__ u32 rk[128];
    __shared__ int sh[256];
    int bu = blockIdx.x, t = threadIdx.x;
    int n0 = bu << BU_SH;
    u32 seg0 = bucketStart[bu], seg1 = bucketStart[bu + 1];
    if (t < 128) { cl[t] = 0; rk[t] = 0; }
    __syncthreads();
    for (u32 i = seg0 + t; i < seg1; i += 256)
        atomicAdd(&cl[pairs[i] >> 17], 1u);  // LDS atomic
    __syncthreads();
    int c = (t < 128) ? (int)cl[t] : 0;
    int val = c;
    sh[t] = val;
    __syncthreads();
#pragma unroll
    for (int off = 1; off < 128; off <<= 1) {
        int y = (t >= off) ? sh[t - off] : 0;
        __syncthreads();
        val += y;
        sh[t] = val;
        __syncthreads();
    }
    if (t < 128) {
        int node = n0 + t;
        u32 st = seg0 + (u32)(val - c);
        sl[t] = st;
        if (node < N_NODES_C) { cnt[node] = c; start[node] = (int)st; }
    }
    __syncthreads();
    for (u32 i = seg0 + t; i < seg1; i += 256) {
        u32 pr = pairs[i];
        u32 loc = pr >> 17;
        u32 r = atomicAdd(&rk[loc], 1u);  // LDS atomic
        col[sl[loc] + r] = (int)(pr & 0x1ffffu);
    }
}

// ------------------- xw1: fused x->bf16 convert + GEMM1 + dinv ------------
// One wave per 16-row strip; loads x as f32 and packs MFMA A-frags in
// registers (Xb intermediate eliminated: -25.6 MB round-trip).
__device__ __forceinline__ frag_ab cvt8(const float* __restrict__ p) {
    float4 f0 = *(const float4*)p;
    float4 f1 = *(const float4*)(p + 4);
    frag_ab r;
    r[0] = (short)f2bf(f0.x); r[1] = (short)f2bf(f0.y);
    r[2] = (short)f2bf(f0.z); r[3] = (short)f2bf(f0.w);
    r[4] = (short)f2bf(f1.x); r[5] = (short)f2bf(f1.y);
    r[6] = (short)f2bf(f1.z); r[7] = (short)f2bf(f1.w);
    return r;
}

__global__ void __launch_bounds__(256) k_xw1(
        const float* __restrict__ x, const u16* __restrict__ Wb,
        const int* __restrict__ cnt, u16* __restrict__ T) {
    int lane = threadIdx.x & 63;
    int q = lane >> 4, ln = lane & 15;
    int wave = blockIdx.x * 4 + (threadIdx.x >> 6);
    if (wave >= NSTRIP_C) return;
    frag_ab bfr[4][2];
#pragma unroll
    for (int nt = 0; nt < 4; ++nt)
#pragma unroll
        for (int kh = 0; kh < 2; ++kh)
            bfr[nt][kh] = *(const frag_ab*)(Wb + (nt * 16 + ln) * 64 + kh * 32 + q * 8);
    int r0 = wave * 16;
    const float* xr = x + (size_t)(r0 + ln) * 64;
    frag_ab a0 = cvt8(xr + q * 8);
    frag_ab a1 = cvt8(xr + 32 + q * 8);
    f32x4 acc[4];
#pragma unroll
    for (int nt = 0; nt < 4; ++nt) {
        acc[nt] = (f32x4){0.f, 0.f, 0.f, 0.f};
        acc[nt] = __builtin_amdgcn_mfma_f32_16x16x32_bf16(a0, bfr[nt][0], acc[nt], 0, 0, 0);
        acc[nt] = __builtin_amdgcn_mfma_f32_16x16x32_bf16(a1, bfr[nt][1], acc[nt], 0, 0, 0);
    }
    float di[4];
#pragma unroll
    for (int reg = 0; reg < 4; ++reg)
        di[reg] = rsqrtf((float)(cnt[r0 + q * 4 + reg] + 1));
#pragma unroll
    for (int nt = 0; nt < 4; ++nt)
#pragma unroll
        for (int reg = 0; reg < 4; ++reg)
            T[(size_t)(r0 + q * 4 + reg) * 64 + nt * 16 + ln] =
                f2bf(acc[nt][reg] * di[reg]);
}

// ------------------- g1w2: fused gather1 + BN/ReLU + GEMM2 + dinv ---------
// One wave per 16-node strip. Per node: CSR gather (4 rows/load, zero-row
// padding), BN+ReLU; h==0 lanes stage the bf16 row in a bank-XOR-swizzled
// per-wave LDS tile (byte ^= (row&7)<<4 on both sides; conflict-free for
// the 8-B writes and the b128 frag reads). After 16 nodes: 8 MFMAs with W2
// frags, dinv from per-strip LDS table, write T2. Ab round-trip (-25.6 MB)
// and the separate gemm2 launch are eliminated.
__global__ void __launch_bounds__(256) k_g1w2(
        const u16* __restrict__ T, const int* __restrict__ col,
        const int* __restrict__ cnt, const int* __restrict__ start,
        const u16* __restrict__ Wb2,
        const float* __restrict__ b, const float* __restrict__ g,
        const float* __restrict__ be, const float* __restrict__ m,
        const float* __restrict__ v, u16* __restrict__ T2) {
    __shared__ u16 abuf[4][16][64];
    __shared__ float dibuf[4][16];
    const int ZROW = N_NODES_C;
    int lane = threadIdx.x & 63;
    int widx = threadIdx.x >> 6;
    int h = lane >> 4, c = lane & 15;   // h==q, c==ln for the MFMA phase
    int cbase = c << 2;
    float scv[4], c0v[4];
#pragma unroll
    for (int i = 0; i < 4; ++i) {
        float sci = g[cbase + i] * rsqrtf(v[cbase + i] + BN_EPS_C);
        scv[i] = sci;
        c0v[i] = (b[cbase + i] - m[cbase + i]) * sci + be[cbase + i];
    }
    int wave = blockIdx.x * 4 + widx;
    if (wave >= NSTRIP_C) return;
    int r0 = wave * 16;
    char* ab = (char*)&abuf[widx][0][0];

    // pipeline prologue: meta for r0, r0+1; col vector for r0
    int d0 = cnt[r0];
    int s0 = start[r0];
    int d1 = cnt[r0 + 1], s1 = start[r0 + 1];
    int cv0 = col[(size_t)(u32)s0 + lane];

    for (int i = 0; i < 16; ++i) {
        int p = r0 + i;
        int deg = __builtin_amdgcn_readfirstlane(d0);
        int cvR = cv0;
        if (i + 1 < 16) {  // rotate pipeline
            cv0 = col[(size_t)(u32)s1 + lane];
            d0 = d1;
            if (i + 2 < 16) { d1 = cnt[p + 2]; s1 = start[p + 2]; }
        }
        if (deg > 63) deg = 63;
        int cv = (lane < deg) ? cvR : ((lane == deg) ? p : ZROW);
        int iters = (deg + 4) >> 2;  // ceil((deg+1)/4), slots incl. self
        float a0 = 0.f, a1 = 0.f, a2 = 0.f, a3 = 0.f;
        int sl = h;
        int j = 0;
        for (; j + 2 <= iters; j += 2) {
            int i0 = __shfl(cv, sl);
            int i1 = __shfl(cv, sl + 4);
            uint2 t0 = *(const uint2*)(T + (((size_t)(u32)i0) << 6) + (c << 2));
            uint2 t1 = *(const uint2*)(T + (((size_t)(u32)i1) << 6) + (c << 2));
            a0 += __uint_as_float(t0.x << 16); a1 += __uint_as_float(t0.x & 0xffff0000u);
            a2 += __uint_as_float(t0.y << 16); a3 += __uint_as_float(t0.y & 0xffff0000u);
            a0 += __uint_as_float(t1.x << 16); a1 += __uint_as_float(t1.x & 0xffff0000u);
            a2 += __uint_as_float(t1.y << 16); a3 += __uint_as_float(t1.y & 0xffff0000u);
            sl += 8;
        }
        if (j < iters) {
            int i0 = __shfl(cv, sl);
            uint2 t0 = *(const uint2*)(T + (((size_t)(u32)i0) << 6) + (c << 2));
            a0 += __uint_as_float(t0.x << 16); a1 += __uint_as_float(t0.x & 0xffff0000u);
            a2 += __uint_as_float(t0.y << 16); a3 += __uint_as_float(t0.y & 0xffff0000u);
        }
        // reduce across the 4 h-groups
        a0 += __shfl_xor(a0, 16); a0 += __shfl_xor(a0, 32);
        a1 += __shfl_xor(a1, 16); a1 += __shfl_xor(a1, 32);
        a2 += __shfl_xor(a2, 16); a2 += __shfl_xor(a2, 32);
        a3 += __shfl_xor(a3, 16); a3 += __shfl_xor(a3, 32);
        float dr = rsqrtf((float)(deg + 1));
        float v0 = fmaxf(fmaf(a0 * dr, scv[0], c0v[0]), 0.f);
        float v1 = fmaxf(fmaf(a1 * dr, scv[1], c0v[1]), 0.f);
        float v2 = fmaxf(fmaf(a2 * dr, scv[2], c0v[2]), 0.f);
        float v3 = fmaxf(fmaf(a3 * dr, scv[3], c0v[3]), 0.f);
        if (h == 0) {
            u32 w0 = (u32)f2bf(v0) | ((u32)f2bf(v1) << 16);
            u32 w1 = (u32)f2bf(v2) | ((u32)f2bf(v3) << 16);
            int boff = i * 128 + ((c * 8) ^ ((i & 7) << 4));  // swizzled
            *(uint2*)(ab + boff) = make_uint2(w0, w1);
            if (c == 0) dibuf[widx][i] = dr;
        }
    }

    // ---- GEMM2 phase: A frags from swizzled LDS, B frags from Wb2 --------
    int q = h, ln = c;
    frag_ab bfr[4][2];
#pragma unroll
    for (int nt = 0; nt < 4; ++nt)
#pragma unroll
        for (int kh = 0; kh < 2; ++kh)
            bfr[nt][kh] = *(const frag_ab*)(Wb2 + (nt * 16 + ln) * 64 + kh * 32 + q * 8);
    int sw = (ln & 7) << 4;
    frag_ab fa0 = *(const frag_ab*)(ab + ln * 128 + ((q * 16) ^ sw));
    frag_ab fa1 = *(const frag_ab*)(ab + ln * 128 + ((64 + q * 16) ^ sw));
    f32x4 acc[4];
#pragma unroll
    for (int nt = 0; nt < 4; ++nt) {
        acc[nt] = (f32x4){0.f, 0.f, 0.f, 0.f};
        acc[nt] = __builtin_amdgcn_mfma_f32_16x16x32_bf16(fa0, bfr[nt][0], acc[nt], 0, 0, 0);
        acc[nt] = __builtin_amdgcn_mfma_f32_16x16x32_bf16(fa1, bfr[nt][1], acc[nt], 0, 0, 0);
    }
    float di[4];
#pragma unroll
    for (int reg = 0; reg < 4; ++reg)
        di[reg] = dibuf[widx][q * 4 + reg];
#pragma unroll
    for (int nt = 0; nt < 4; ++nt)
#pragma unroll
        for (int reg = 0; reg < 4; ++reg)
            T2[(size_t)(r0 + q * 4 + reg) * 64 + nt * 16 + ln] =
                f2bf(acc[nt][reg] * di[reg]);
}

// ------------------- gather2: CSR gather + BN/ReLU + mean-pool ------------
__global__ void __launch_bounds__(256) k_gather2(
        const u16* __restrict__ T, const int* __restrict__ col,
        const int* __restrict__ cnt, const int* __restrict__ start,
        const float* __restrict__ b, const float* __restrict__ g,
        const float* __restrict__ be, const float* __restrict__ m,
        const float* __restrict__ v, const int* __restrict__ batch,
        float* __restrict__ pooled) {
    const int ZROW = N_NODES_C;
    int lane = threadIdx.x & 63;
    int h = lane >> 4, c = lane & 15;
    int cbase = c << 2;
    int wave = blockIdx.x * 4 + (threadIdx.x >> 6);
    int nwaves = gridDim.x * 4;
    float scv[4], c0v[4];
#pragma unroll
    for (int i = 0; i < 4; ++i) {
        float sci = g[cbase + i] * rsqrtf(v[cbase + i] + BN_EPS_C);
        scv[i] = sci;
        c0v[i] = (b[cbase + i] - m[cbase + i]) * sci + be[cbase + i];
    }
    const int chunk = (N_NODES_C + nwaves - 1) / nwaves;
    int p0 = wave * chunk;
    int p1 = p0 + chunk; if (p1 > N_NODES_C) p1 = N_NODES_C;
    if (p0 >= p1) return;

    float psum = 0.f; int curg = -1;

    int d0 = cnt[p0];
    int s0 = start[p0];
    int d1 = 0, s1 = 0;
    if (p0 + 1 < p1) { d1 = cnt[p0 + 1]; s1 = start[p0 + 1]; }
    int cv0 = col[(size_t)(u32)s0 + lane];

    for (int p = p0; p < p1; ++p) {
        int deg = __builtin_amdgcn_readfirstlane(d0);
        int cvR = cv0;
        if (p + 1 < p1) {
            cv0 = col[(size_t)(u32)s1 + lane];
            d0 = d1;
            if (p + 2 < p1) { d1 = cnt[p + 2]; s1 = start[p + 2]; }
        }
        if (deg > 63) deg = 63;
        int cv = (lane < deg) ? cvR : ((lane == deg) ? p : ZROW);
        int iters = (deg + 4) >> 2;
        float a0 = 0.f, a1 = 0.f, a2 = 0.f, a3 = 0.f;
        int sl = h;
        int j = 0;
        for (; j + 2 <= iters; j += 2) {
            int i0 = __shfl(cv, sl);
            int i1 = __shfl(cv, sl + 4);
            uint2 t0 = *(const uint2*)(T + (((size_t)(u32)i0) << 6) + (c << 2));
            uint2 t1 = *(const uint2*)(T + (((size_t)(u32)i1) << 6) + (c << 2));
            a0 += __uint_as_float(t0.x << 16); a1 += __uint_as_float(t0.x & 0xffff0000u);
            a2 += __uint_as_float(t0.y << 16); a3 += __uint_as_float(t0.y & 0xffff0000u);
            a0 += __uint_as_float(t1.x << 16); a1 += __uint_as_float(t1.x & 0xffff0000u);
            a2 += __uint_as_float(t1.y << 16); a3 += __uint_as_float(t1.y & 0xffff0000u);
            sl += 8;
        }
        if (j < iters) {
            int i0 = __shfl(cv, sl);
            uint2 t0 = *(const uint2*)(T + (((size_t)(u32)i0) << 6) + (c << 2));
            a0 += __uint_as_float(t0.x << 16); a1 += __uint_as_float(t0.x & 0xffff0000u);
            a2 += __uint_as_float(t0.y << 16); a3 += __uint_as_float(t0.y & 0xffff0000u);
        }
        a0 += __shfl_xor(a0, 16); a0 += __shfl_xor(a0, 32);
        a1 += __shfl_xor(a1, 16); a1 += __shfl_xor(a1, 32);
        a2 += __shfl_xor(a2, 16); a2 += __shfl_xor(a2, 32);
        a3 += __shfl_xor(a3, 16); a3 += __shfl_xor(a3, 32);
        float dr = rsqrtf((float)(deg + 1));
        float asel = (h & 2) ? ((h & 1) ? a3 : a2) : ((h & 1) ? a1 : a0);
        float scl  = (h & 2) ? ((h & 1) ? scv[3] : scv[2]) : ((h & 1) ? scv[1] : scv[0]);
        float c0l  = (h & 2) ? ((h & 1) ? c0v[3] : c0v[2]) : ((h & 1) ? c0v[1] : c0v[0]);
        float vh = fmaxf(fmaf(asel * dr, scl, c0l), 0.f);
        int gg = batch[p];
        if (gg != curg) {
            if (curg >= 0) atomicAdd(&pooled[curg * 64 + cbase + h], psum);
            curg = gg; psum = 0.f;
        }
        psum += vh;
    }
    if (curg >= 0) atomicAdd(&pooled[curg * 64 + cbase + h], psum);
}

// ----------------------------- classifier --------------------------------
__global__ void k_final(const float* __restrict__ pooled, const int* __restrict__ batch,
                        const float* __restrict__ Wc, const float* __restrict__ bc,
                        float* __restrict__ out) {
    __shared__ float sp[64 * 65];
    __shared__ int sub[64];
    int t = threadIdx.x;  // 256 threads
    for (int i = t; i < 4096; i += 256) sp[(i >> 6) * 65 + (i & 63)] = pooled[i];
    if (t < 64) {
        int lo = 0, hi = N_NODES_C;
        while (lo < hi) { int mid = (lo + hi) >> 1; if (batch[mid] > t) hi = mid; else lo = mid + 1; }
        sub[t] = lo;  // first index with batch > t
    }
    __syncthreads();
    if (t < 64) {
        int gi = t;
        int lb = gi ? sub[gi - 1] : 0;
        int cntg = sub[gi] - lb;
        float inv = 1.0f / fmaxf((float)cntg, 1.0f);
        float a0 = 0.f, a1 = 0.f;
#pragma unroll 8
        for (int f = 0; f < 64; ++f) {
            float p = sp[gi * 65 + f];
            a0 = fmaf(p, Wc[f * 2 + 0], a0);
            a1 = fmaf(p, Wc[f * 2 + 1], a1);
        }
        out[gi * 2 + 0] = a0 * inv + bc[0];
        out[gi * 2 + 1] = a1 * inv + bc[1];
    }
}

extern "C" void kernel_launch(void* const* d_in, const int* in_sizes, int n_in,
                              void* d_out, int out_size, void* d_ws, size_t ws_size,
                              hipStream_t stream) {
    const float* x    = (const float*)d_in[0];
    const int*   ei   = (const int*)d_in[1];
    const int*   batch= (const int*)d_in[2];
    const float* W1 = (const float*)d_in[3];
    const float* b1 = (const float*)d_in[4];
    const float* g1 = (const float*)d_in[5];
    const float* be1= (const float*)d_in[6];
    const float* m1 = (const float*)d_in[7];
    const float* v1 = (const float*)d_in[8];
    const float* W2 = (const float*)d_in[9];
    const float* b2 = (const float*)d_in[10];
    const float* g2 = (const float*)d_in[11];
    const float* be2= (const float*)d_in[12];
    const float* m2 = (const float*)d_in[13];
    const float* v2 = (const float*)d_in[14];
    const float* Wc = (const float*)d_in[15];
    const float* bc = (const float*)d_in[16];
    float* out = (float*)d_out;

    char* ws = (char*)d_ws;
    size_t off = 0;
    auto alloc = [&](size_t bytes) {
        size_t o = off;
        off = (off + bytes + 511) & ~(size_t)511;
        return o;
    };
    size_t o_pool  = alloc((size_t)NUM_GRAPHS_C * D_C * 4);
    size_t zero_bytes = off;  // only pooled zeroed each call
    size_t o_hist  = alloc((size_t)PART_B * NB_C * 4);     // 1.6 MB
    size_t o_ploc  = alloc((size_t)PART_B * NB_C * 4);     // 1.6 MB
    size_t o_btot  = alloc((size_t)NB_C * 4);
    size_t o_bst   = alloc((size_t)(NB_C + 2) * 4);
    size_t o_pairs = alloc((size_t)N_EDGES_C * 4);         // 4.8 MB packed
    size_t o_cnt   = alloc((size_t)N_NODES_C * 4);
    size_t o_start = alloc((size_t)(N_NODES_C + 64) * 4);
    size_t o_col   = alloc((size_t)(N_EDGES_C + 64) * 4);  // CSR 4.8 MB (+pad)
    size_t o_wb1   = alloc(4096 * 2);
    size_t o_wb2   = alloc(4096 * 2);
    size_t o_t     = alloc((size_t)(N_NODES_C + 1) * D_C * 2);  // +1: zero row
    size_t o_t2    = alloc((size_t)(N_NODES_C + 1) * D_C * 2);  // +1: zero row
    (void)ws_size; (void)in_sizes; (void)n_in; (void)out_size;

    float* pooled = (float*)(ws + o_pool);
    u32*   hist   = (u32*)(ws + o_hist);
    u32*   ploc   = (u32*)(ws + o_ploc);
    u32*   btot   = (u32*)(ws + o_btot);
    u32*   bst    = (u32*)(ws + o_bst);
    u32*   pairs  = (u32*)(ws + o_pairs);
    int*   cnt    = (int*)(ws + o_cnt);
    int*   startp = (int*)(ws + o_start);
    int*   col    = (int*)(ws + o_col);
    u16*   Wb1    = (u16*)(ws + o_wb1);
    u16*   Wb2    = (u16*)(ws + o_wb2);
    u16*   T      = (u16*)(ws + o_t);
    u16*   T2     = (u16*)(ws + o_t2);

    const int* srcp = ei;
    const int* dstp = ei + N_EDGES_C;

    hipMemsetAsync(ws, 0, zero_bytes, stream);

    int gblocks = 2048;   // 8192 persistent waves (gather2)
    int mblocks = 1563;   // 6252 waves: one 16-row strip each
    k_prepW<<<16, 256, 0, stream>>>(W1, W2, Wb1, Wb2, T, T2);
    k_hist<<<PART_B, 256, 0, stream>>>(dstp, hist);
    k_pscan<<<(NB_C + 3) / 4, 256, 0, stream>>>(hist, ploc, btot);
    k_bscan<<<1, 1024, 0, stream>>>(btot, bst);
    k_part<<<PART_B, 256, 0, stream>>>(srcp, dstp, ploc, bst, pairs);
    k_csr<<<NB_C, 256, 0, stream>>>(pairs, bst, cnt, startp, col);

    k_xw1<<<mblocks, 256, 0, stream>>>(x, Wb1, cnt, T);
    k_g1w2<<<mblocks, 256, 0, stream>>>(T, col, cnt, startp, Wb2,
                                        b1, g1, be1, m1, v1, T2);
    k_gather2<<<gblocks, 256, 0, stream>>>(T2, col, cnt, startp, b2, g2, be2, m2, v2,
                                           batch, pooled);
    k_final<<<1, 256, 0, stream>>>(pooled, batch, Wc, bc, out);
}